// Round 1
// baseline (191.498 us; speedup 1.0000x reference)
//
#include <hip/hip_runtime.h>

typedef __attribute__((ext_vector_type(8))) short bf16x8;
typedef __attribute__((ext_vector_type(4))) float floatx4;

#define NB 128
#define NT 256
#define NC 384
#define NH 8
#define ND 48

static __device__ __forceinline__ unsigned short f2bf(float f) {
  unsigned int u = __float_as_uint(f);
  return (unsigned short)((u + 0x7fffu + ((u >> 16) & 1u)) >> 16);
}

// ---------------- Kernel 1: qkv = x @ W_qkv + b_qkv -> bf16 [3][B][H][T][48]
__global__ __launch_bounds__(256) void k_qkv(const float* __restrict__ x,
                                             const float* __restrict__ Wq,
                                             const float* __restrict__ bq,
                                             unsigned short* __restrict__ qkv) {
  __shared__ __align__(16) unsigned short As[128 * 40];  // [m][k] pad 40
  __shared__ __align__(16) unsigned short Bs[128 * 40];  // [n][k] transposed
  const int t = threadIdx.x;
  const int lane = t & 63, w = t >> 6;
  const int wm = w >> 1, wn = w & 1;
  const int lq = lane & 15, lg = lane >> 4;
  const int m0 = blockIdx.x * 128;
  const int n0 = blockIdx.y * 128;
  floatx4 acc[4][4] = {};

  const int ar = t >> 1, aseg = (t & 1) * 16;
  const int bk = t >> 3, bns = (t & 7) * 16;

  for (int k0 = 0; k0 < 384; k0 += 32) {
    __syncthreads();
    {  // stage A tile 128x32 fp32 -> bf16
      const float* src = x + (size_t)(m0 + ar) * 384 + k0 + aseg;
      float v[16];
#pragma unroll
      for (int i = 0; i < 4; ++i) *(float4*)&v[i * 4] = ((const float4*)src)[i];
      bf16x8 p0, p1;
#pragma unroll
      for (int i = 0; i < 8; ++i) { p0[i] = f2bf(v[i]); p1[i] = f2bf(v[8 + i]); }
      *(bf16x8*)&As[ar * 40 + aseg] = p0;
      *(bf16x8*)&As[ar * 40 + aseg + 8] = p1;
    }
    {  // stage B tile 32x128 fp32 -> bf16, transposed [n][k]
      const float* src = Wq + (size_t)(k0 + bk) * 1152 + n0 + bns;
      float v[16];
#pragma unroll
      for (int i = 0; i < 4; ++i) *(float4*)&v[i * 4] = ((const float4*)src)[i];
#pragma unroll
      for (int i = 0; i < 16; ++i) Bs[(bns + i) * 40 + bk] = f2bf(v[i]);
    }
    __syncthreads();
    bf16x8 a[4], b[4];
#pragma unroll
    for (int mt = 0; mt < 4; ++mt)
      a[mt] = *(const bf16x8*)&As[(wm * 64 + mt * 16 + lq) * 40 + lg * 8];
#pragma unroll
    for (int nt = 0; nt < 4; ++nt)
      b[nt] = *(const bf16x8*)&Bs[(wn * 64 + nt * 16 + lq) * 40 + lg * 8];
#pragma unroll
    for (int mt = 0; mt < 4; ++mt)
#pragma unroll
      for (int nt = 0; nt < 4; ++nt)
        acc[mt][nt] = __builtin_amdgcn_mfma_f32_16x16x32_bf16(a[mt], b[nt], acc[mt][nt], 0, 0, 0);
  }
  // epilogue: +bias, scatter to [comp][b][h][t][d] bf16
  const int comp = n0 / 384;
  const int cb = n0 - comp * 384;
#pragma unroll
  for (int nt = 0; nt < 4; ++nt) {
    const int cc = cb + wn * 64 + nt * 16 + lq;  // 0..383 within comp
    const int h = cc / 48, d = cc - h * 48;
    const float bias = bq[n0 + wn * 64 + nt * 16 + lq];
#pragma unroll
    for (int mt = 0; mt < 4; ++mt) {
#pragma unroll
      for (int j = 0; j < 4; ++j) {
        const int row = m0 + wm * 64 + mt * 16 + lg * 4 + j;
        const int bb = row >> 8, tt = row & 255;
        qkv[((((size_t)comp * NB + bb) * NH + h) * NT + tt) * ND + d] =
            f2bf(acc[mt][nt][j] + bias);
      }
    }
  }
}

// ---------------- Kernel 2: windowed causal attention + gate, bf16 out [B][T][C]
__global__ __launch_bounds__(256) void k_attn(const unsigned short* __restrict__ qkv,
                                              const float* __restrict__ gate,
                                              unsigned short* __restrict__ attg) {
  __shared__ __align__(16) unsigned short Ks[128 * 72];   // [key][hd pad 64->72]
  __shared__ __align__(16) unsigned short Vt[48 * 152];   // [d][key pad 144->152]
  __shared__ __align__(16) unsigned short Ps[4 * 16 * 104];  // per-wave P [q][key pad]
  const int t = threadIdx.x;
  const int blk = blockIdx.x;
  const int tile = blk & 3;
  const int bh = blk >> 2;
  const int b = bh >> 3, h = bh & 7;
  const int base = tile * 64;
  const size_t kvoff = (size_t)bh * NT * ND;
  const unsigned short* qptr = qkv + kvoff;
  const unsigned short* kptr = qkv + (size_t)NB * NH * NT * ND + kvoff;
  const unsigned short* vptr = qkv + (size_t)2 * NB * NH * NT * ND + kvoff;

  if (t < 48) {  // zero V pad columns 128..143 (read by padded PV chunk)
    bf16x8 z = {};
    *(bf16x8*)&Vt[t * 152 + 128] = z;
    *(bf16x8*)&Vt[t * 152 + 136] = z;
  }
  if (t < 128) {  // stage K rows (keys base-64 .. base+63), hd zero-padded to 64
    const int r = t, ka = base - 64 + r;
    unsigned short* dst = &Ks[r * 72];
    if (ka >= 0) {
      const unsigned short* src = kptr + (size_t)ka * ND;
#pragma unroll
      for (int i = 0; i < 6; ++i) *(bf16x8*)(dst + i * 8) = *(const bf16x8*)(src + i * 8);
      bf16x8 z = {};
      *(bf16x8*)(dst + 48) = z;
      *(bf16x8*)(dst + 56) = z;
    } else {
      bf16x8 z = {};
#pragma unroll
      for (int i = 0; i < 8; ++i) *(bf16x8*)(dst + i * 8) = z;
    }
  } else {  // stage V transposed [d][key]
    const int r = t - 128, ka = base - 64 + r;
    if (ka >= 0) {
      const unsigned short* src = vptr + (size_t)ka * ND;
      bf16x8 vv[6];
#pragma unroll
      for (int i = 0; i < 6; ++i) vv[i] = *(const bf16x8*)(src + i * 8);
#pragma unroll
      for (int i = 0; i < 6; ++i)
#pragma unroll
        for (int j = 0; j < 8; ++j)
          Vt[(i * 8 + j) * 152 + r] = (unsigned short)vv[i][j];
    } else {
#pragma unroll
      for (int d = 0; d < 48; ++d) Vt[d * 152 + r] = 0;
    }
  }
  __syncthreads();

  const int lane = t & 63, w = t >> 6;
  const int lq = lane & 15, lg = lane >> 4;
  const int qs = base + w * 16;

  // Q fragments from global (row = query, k = hd; hd 48..63 zero)
  const unsigned short* qrow = qptr + (size_t)(qs + lq) * ND;
  bf16x8 aq0 = *(const bf16x8*)(qrow + lg * 8);
  bf16x8 aq1 = {};
  if (lg < 2) aq1 = *(const bf16x8*)(qrow + 32 + lg * 8);

  // S = Q K^T over 5 key-subtiles (80-key window)
  floatx4 s[5];
#pragma unroll
  for (int kt = 0; kt < 5; ++kt) {
    const unsigned short* kr = &Ks[(w * 16 + kt * 16 + lq) * 72];
    bf16x8 kb0 = *(const bf16x8*)(kr + lg * 8);
    bf16x8 kb1 = *(const bf16x8*)(kr + 32 + lg * 8);
    floatx4 z = {};
    z = __builtin_amdgcn_mfma_f32_16x16x32_bf16(aq0, kb0, z, 0, 0, 0);
    z = __builtin_amdgcn_mfma_f32_16x16x32_bf16(aq1, kb1, z, 0, 0, 0);
    s[kt] = z;
  }

  const float scale = 0.14433756729740643f;  // 1/sqrt(48)
  floatx4 pj[5];
#pragma unroll
  for (int j = 0; j < 4; ++j) {
    const int qa = qs + lg * 4 + j;
    float mx = -1e30f;
    float sv[5];
    bool ok[5];
#pragma unroll
    for (int kt = 0; kt < 5; ++kt) {
      const int ka = base - 64 + w * 16 + kt * 16 + lq;
      sv[kt] = s[kt][j] * scale;
      ok[kt] = (ka >= 0) && (ka <= qa) && (qa - ka <= 64);
      if (ok[kt]) mx = fmaxf(mx, sv[kt]);
    }
#pragma unroll
    for (int dd = 1; dd < 16; dd <<= 1) mx = fmaxf(mx, __shfl_xor(mx, dd));
    float sum = 0.f;
#pragma unroll
    for (int kt = 0; kt < 5; ++kt) {
      float p = ok[kt] ? __expf(sv[kt] - mx) : 0.f;
      pj[kt][j] = p;
      sum += p;
    }
#pragma unroll
    for (int dd = 1; dd < 16; dd <<= 1) sum += __shfl_xor(sum, dd);
    const float inv = 1.f / sum;
#pragma unroll
    for (int kt = 0; kt < 5; ++kt) pj[kt][j] *= inv;
  }

  // P -> per-wave LDS [16 q][104], keys 80..95 zeroed (pad chunk)
  unsigned short* pw = &Ps[w * 16 * 104];
#pragma unroll
  for (int kt = 0; kt < 5; ++kt)
#pragma unroll
    for (int j = 0; j < 4; ++j)
      pw[(lg * 4 + j) * 104 + kt * 16 + lq] = f2bf(pj[kt][j]);
#pragma unroll
  for (int j = 0; j < 4; ++j) pw[lq * 104 + 80 + lg * 4 + j] = 0;

  // O = P V
  floatx4 o[3] = {};
#pragma unroll
  for (int c = 0; c < 3; ++c) {
    bf16x8 ap = *(const bf16x8*)&pw[lq * 104 + c * 32 + lg * 8];
#pragma unroll
    for (int nt = 0; nt < 3; ++nt) {
      bf16x8 av = *(const bf16x8*)&Vt[(nt * 16 + lq) * 152 + w * 16 + c * 32 + lg * 8];
      o[nt] = __builtin_amdgcn_mfma_f32_16x16x32_bf16(ap, av, o[nt], 0, 0, 0);
    }
  }
  // epilogue: * gate, bf16 store to [b][t][c]
#pragma unroll
  for (int nt = 0; nt < 3; ++nt) {
    const int d = nt * 16 + lq;
    const int c = h * ND + d;
    const float g = gate[c];
#pragma unroll
    for (int j = 0; j < 4; ++j) {
      const int tt = qs + lg * 4 + j;
      attg[((size_t)b * NT + tt) * NC + c] = f2bf(o[nt][j] * g);
    }
  }
}

// ---------------- Kernel 3: out = attg @ W_proj + b_proj (fp32 out)
__global__ __launch_bounds__(256) void k_proj(const unsigned short* __restrict__ A,
                                              const float* __restrict__ Wp,
                                              const float* __restrict__ bp,
                                              float* __restrict__ out) {
  __shared__ __align__(16) unsigned short As[128 * 40];
  __shared__ __align__(16) unsigned short Bs[128 * 40];
  const int t = threadIdx.x;
  const int lane = t & 63, w = t >> 6;
  const int wm = w >> 1, wn = w & 1;
  const int lq = lane & 15, lg = lane >> 4;
  const int m0 = blockIdx.x * 128;
  const int n0 = blockIdx.y * 128;
  floatx4 acc[4][4] = {};
  const int ar = t >> 1, aseg = (t & 1) * 16;
  const int bk = t >> 3, bns = (t & 7) * 16;

  for (int k0 = 0; k0 < 384; k0 += 32) {
    __syncthreads();
    {  // stage A tile 128x32 bf16
      const unsigned short* src = A + (size_t)(m0 + ar) * 384 + k0 + aseg;
      *(bf16x8*)&As[ar * 40 + aseg] = *(const bf16x8*)src;
      *(bf16x8*)&As[ar * 40 + aseg + 8] = *(const bf16x8*)(src + 8);
    }
    {  // stage B tile 32x128 fp32 -> bf16 transposed
      const float* src = Wp + (size_t)(k0 + bk) * 384 + n0 + bns;
      float v[16];
#pragma unroll
      for (int i = 0; i < 4; ++i) *(float4*)&v[i * 4] = ((const float4*)src)[i];
#pragma unroll
      for (int i = 0; i < 16; ++i) Bs[(bns + i) * 40 + bk] = f2bf(v[i]);
    }
    __syncthreads();
    bf16x8 a[4], b[4];
#pragma unroll
    for (int mt = 0; mt < 4; ++mt)
      a[mt] = *(const bf16x8*)&As[(wm * 64 + mt * 16 + lq) * 40 + lg * 8];
#pragma unroll
    for (int nt = 0; nt < 4; ++nt)
      b[nt] = *(const bf16x8*)&Bs[(wn * 64 + nt * 16 + lq) * 40 + lg * 8];
#pragma unroll
    for (int mt = 0; mt < 4; ++mt)
#pragma unroll
      for (int nt = 0; nt < 4; ++nt)
        acc[mt][nt] = __builtin_amdgcn_mfma_f32_16x16x32_bf16(a[mt], b[nt], acc[mt][nt], 0, 0, 0);
  }
#pragma unroll
  for (int nt = 0; nt < 4; ++nt) {
    const int col = n0 + wn * 64 + nt * 16 + lq;
    const float bias = bp[col];
#pragma unroll
    for (int mt = 0; mt < 4; ++mt)
#pragma unroll
      for (int j = 0; j < 4; ++j) {
        const int row = m0 + wm * 64 + mt * 16 + lg * 4 + j;
        out[(size_t)row * 384 + col] = acc[mt][nt][j] + bias;
      }
  }
}

extern "C" void kernel_launch(void* const* d_in, const int* in_sizes, int n_in,
                              void* d_out, int out_size, void* d_ws, size_t ws_size,
                              hipStream_t stream) {
  const float* x    = (const float*)d_in[0];
  const float* Wq   = (const float*)d_in[1];
  const float* bq   = (const float*)d_in[2];
  const float* Wp   = (const float*)d_in[3];
  const float* bp   = (const float*)d_in[4];
  const float* gate = (const float*)d_in[5];

  unsigned short* qkvp = (unsigned short*)d_ws;                 // 3*B*H*T*48 bf16
  unsigned short* attgp = qkvp + (size_t)3 * NB * NH * NT * ND; // B*T*C bf16
  float* out = (float*)d_out;

  k_qkv<<<dim3(256, 9), 256, 0, stream>>>(x, Wq, bq, qkvp);
  k_attn<<<dim3(4096), 256, 0, stream>>>(qkvp, gate, attgp);
  k_proj<<<dim3(256, 3), 256, 0, stream>>>(attgp, Wp, bp, out);
}

// Round 2
// 122.193 us; speedup vs baseline: 1.5672x; 1.5672x over previous
//
#include <hip/hip_runtime.h>

typedef __attribute__((ext_vector_type(8))) short bf16x8;
typedef __attribute__((ext_vector_type(4))) float floatx4;

#define NB 128
#define NT 256
#define NC 384
#define NH 8
#define ND 48

static __device__ __forceinline__ unsigned short f2bf(float f) {
  unsigned int u = __float_as_uint(f);
  return (unsigned short)((u + 0x7fffu + ((u >> 16) & 1u)) >> 16);
}

static __device__ __forceinline__ void gload16(const unsigned short* g, unsigned short* l) {
  __builtin_amdgcn_global_load_lds(
      (const __attribute__((address_space(1))) void*)g,
      (__attribute__((address_space(3))) void*)l, 16, 0, 0);
}

// ---------------- Prep 1: x fp32 -> bf16 (row-major unchanged)
__global__ __launch_bounds__(256) void k_cvt(const float* __restrict__ in,
                                             unsigned short* __restrict__ outp,
                                             int n8) {
  int idx = blockIdx.x * 256 + threadIdx.x;
  const int stride = gridDim.x * 256;
  for (; idx < n8; idx += stride) {
    const float* s = in + (size_t)idx * 8;
    float v[8];
    *(float4*)&v[0] = ((const float4*)s)[0];
    *(float4*)&v[4] = ((const float4*)s)[1];
    bf16x8 p;
#pragma unroll
    for (int i = 0; i < 8; ++i) p[i] = f2bf(v[i]);
    *(bf16x8*)(outp + (size_t)idx * 8) = p;
  }
}

// ---------------- Prep 2: transpose+convert W_qkv -> [1152][384] bf16, W_proj -> [384][384] bf16
__global__ __launch_bounds__(256) void k_twt(const float* __restrict__ Wq,
                                             const float* __restrict__ Wp,
                                             unsigned short* __restrict__ WqT,
                                             unsigned short* __restrict__ WpT) {
  __shared__ float T[64][65];
  int blk = blockIdx.x;
  const float* src;
  unsigned short* dst;
  int N, kt, nt;
  if (blk < 108) { src = Wq; dst = WqT; N = 1152; kt = blk / 18; nt = blk % 18; }
  else { int b2 = blk - 108; src = Wp; dst = WpT; N = 384; kt = b2 / 6; nt = b2 % 6; }
  const int k0 = kt * 64, n0 = nt * 64;
  const int t = threadIdx.x;
  const int r = t >> 2, c = (t & 3) * 16;
  const float* s = src + (size_t)(k0 + r) * N + n0 + c;
#pragma unroll
  for (int i = 0; i < 4; ++i) *(float4*)&T[r][c + i * 4] = ((const float4*)s)[i];
  __syncthreads();
  unsigned short o[16];
#pragma unroll
  for (int i = 0; i < 16; ++i) o[i] = f2bf(T[c + i][r]);
  unsigned short* dp = dst + (size_t)(n0 + r) * 384 + k0 + c;
  *(bf16x8*)dp = *(bf16x8*)&o[0];
  *(bf16x8*)(dp + 8) = *(bf16x8*)&o[8];
}

// ---------------- Kernel 1: qkv = xb @ WqT^T + b_qkv -> bf16 [3][B][H][T][48]
__global__ __launch_bounds__(256) void k_qkv(const unsigned short* __restrict__ xb,
                                             const unsigned short* __restrict__ WqT,
                                             const float* __restrict__ bq,
                                             unsigned short* __restrict__ qkv) {
  __shared__ __align__(16) unsigned short As[128 * 32];
  __shared__ __align__(16) unsigned short Bs[128 * 32];
  const int t = threadIdx.x, lane = t & 63, w = t >> 6;
  const int wm = w >> 1, wn = w & 1;
  const int lq = lane & 15, lg = lane >> 4;
  const int m0 = blockIdx.x * 128, n0 = blockIdx.y * 128;
  const unsigned short* Ag = xb + (size_t)(m0 + w * 32 + (lane >> 2)) * 384 + (lane & 3) * 8;
  const unsigned short* Bg = WqT + (size_t)(n0 + w * 32 + (lane >> 2)) * 384 + (lane & 3) * 8;
  unsigned short* lA0 = As + (w * 32) * 32;
  unsigned short* lA1 = As + (w * 32 + 16) * 32;
  unsigned short* lB0 = Bs + (w * 32) * 32;
  unsigned short* lB1 = Bs + (w * 32 + 16) * 32;
  floatx4 acc[4][4] = {};

  for (int k0 = 0; k0 < 384; k0 += 32) {
    __syncthreads();
    gload16(Ag + k0, lA0);
    gload16(Ag + k0 + 16 * 384, lA1);
    gload16(Bg + k0, lB0);
    gload16(Bg + k0 + 16 * 384, lB1);
    __syncthreads();
    bf16x8 a[4], b[4];
#pragma unroll
    for (int mt = 0; mt < 4; ++mt)
      a[mt] = *(const bf16x8*)&As[(wm * 64 + mt * 16 + lq) * 32 + lg * 8];
#pragma unroll
    for (int nt = 0; nt < 4; ++nt)
      b[nt] = *(const bf16x8*)&Bs[(wn * 64 + nt * 16 + lq) * 32 + lg * 8];
#pragma unroll
    for (int mt = 0; mt < 4; ++mt)
#pragma unroll
      for (int nt = 0; nt < 4; ++nt)
        acc[mt][nt] = __builtin_amdgcn_mfma_f32_16x16x32_bf16(a[mt], b[nt], acc[mt][nt], 0, 0, 0);
  }
  // epilogue: +bias, scatter to [comp][b][h][t][d] bf16
  const int comp = n0 / 384;
  const int cb = n0 - comp * 384;
#pragma unroll
  for (int nt = 0; nt < 4; ++nt) {
    const int cc = cb + wn * 64 + nt * 16 + lq;
    const int h = cc / 48, d = cc - h * 48;
    const float bias = bq[n0 + wn * 64 + nt * 16 + lq];
#pragma unroll
    for (int mt = 0; mt < 4; ++mt) {
#pragma unroll
      for (int j = 0; j < 4; ++j) {
        const int row = m0 + wm * 64 + mt * 16 + lg * 4 + j;
        const int bb = row >> 8, tt = row & 255;
        qkv[((((size_t)comp * NB + bb) * NH + h) * NT + tt) * ND + d] =
            f2bf(acc[mt][nt][j] + bias);
      }
    }
  }
}

// ---------------- Kernel 2: windowed causal attention + gate, bf16 out [B][T][C]
__global__ __launch_bounds__(256) void k_attn(const unsigned short* __restrict__ qkv,
                                              const float* __restrict__ gate,
                                              unsigned short* __restrict__ attg) {
  __shared__ __align__(16) unsigned short Ks[128 * 72];      // [key][hd pad 64->72]
  __shared__ __align__(16) unsigned short Vt[48 * 152];      // [d][key pad 144->152]
  __shared__ __align__(16) unsigned short Ps[4 * 16 * 104];  // per-wave P [q][key pad]
  const int t = threadIdx.x;
  const int blk = blockIdx.x;
  const int tile = blk & 3;
  const int bh = blk >> 2;
  const int b = bh >> 3, h = bh & 7;
  const int base = tile * 64;
  const size_t kvoff = (size_t)bh * NT * ND;
  const unsigned short* qptr = qkv + kvoff;
  const unsigned short* kptr = qkv + (size_t)NB * NH * NT * ND + kvoff;
  const unsigned short* vptr = qkv + (size_t)2 * NB * NH * NT * ND + kvoff;

  if (t < 48) {
    bf16x8 z = {};
    *(bf16x8*)&Vt[t * 152 + 128] = z;
    *(bf16x8*)&Vt[t * 152 + 136] = z;
  }
  if (t < 128) {
    const int r = t, ka = base - 64 + r;
    unsigned short* dst = &Ks[r * 72];
    if (ka >= 0) {
      const unsigned short* src = kptr + (size_t)ka * ND;
#pragma unroll
      for (int i = 0; i < 6; ++i) *(bf16x8*)(dst + i * 8) = *(const bf16x8*)(src + i * 8);
      bf16x8 z = {};
      *(bf16x8*)(dst + 48) = z;
      *(bf16x8*)(dst + 56) = z;
    } else {
      bf16x8 z = {};
#pragma unroll
      for (int i = 0; i < 8; ++i) *(bf16x8*)(dst + i * 8) = z;
    }
  } else {
    const int r = t - 128, ka = base - 64 + r;
    if (ka >= 0) {
      const unsigned short* src = vptr + (size_t)ka * ND;
      bf16x8 vv[6];
#pragma unroll
      for (int i = 0; i < 6; ++i) vv[i] = *(const bf16x8*)(src + i * 8);
#pragma unroll
      for (int i = 0; i < 6; ++i)
#pragma unroll
        for (int j = 0; j < 8; ++j)
          Vt[(i * 8 + j) * 152 + r] = (unsigned short)vv[i][j];
    } else {
#pragma unroll
      for (int d = 0; d < 48; ++d) Vt[d * 152 + r] = 0;
    }
  }
  __syncthreads();

  const int lane = t & 63, w = t >> 6;
  const int lq = lane & 15, lg = lane >> 4;
  const int qs = base + w * 16;

  const unsigned short* qrow = qptr + (size_t)(qs + lq) * ND;
  bf16x8 aq0 = *(const bf16x8*)(qrow + lg * 8);
  bf16x8 aq1 = {};
  if (lg < 2) aq1 = *(const bf16x8*)(qrow + 32 + lg * 8);

  floatx4 s[5];
#pragma unroll
  for (int kt = 0; kt < 5; ++kt) {
    const unsigned short* kr = &Ks[(w * 16 + kt * 16 + lq) * 72];
    bf16x8 kb0 = *(const bf16x8*)(kr + lg * 8);
    bf16x8 kb1 = *(const bf16x8*)(kr + 32 + lg * 8);
    floatx4 z = {};
    z = __builtin_amdgcn_mfma_f32_16x16x32_bf16(aq0, kb0, z, 0, 0, 0);
    z = __builtin_amdgcn_mfma_f32_16x16x32_bf16(aq1, kb1, z, 0, 0, 0);
    s[kt] = z;
  }

  const float scale = 0.14433756729740643f;  // 1/sqrt(48)
  floatx4 pj[5];
#pragma unroll
  for (int j = 0; j < 4; ++j) {
    const int qa = qs + lg * 4 + j;
    float mx = -1e30f;
    float sv[5];
    bool ok[5];
#pragma unroll
    for (int kt = 0; kt < 5; ++kt) {
      const int ka = base - 64 + w * 16 + kt * 16 + lq;
      sv[kt] = s[kt][j] * scale;
      ok[kt] = (ka >= 0) && (ka <= qa) && (qa - ka <= 64);
      if (ok[kt]) mx = fmaxf(mx, sv[kt]);
    }
#pragma unroll
    for (int dd = 1; dd < 16; dd <<= 1) mx = fmaxf(mx, __shfl_xor(mx, dd));
    float sum = 0.f;
#pragma unroll
    for (int kt = 0; kt < 5; ++kt) {
      float p = ok[kt] ? __expf(sv[kt] - mx) : 0.f;
      pj[kt][j] = p;
      sum += p;
    }
#pragma unroll
    for (int dd = 1; dd < 16; dd <<= 1) sum += __shfl_xor(sum, dd);
    const float inv = 1.f / sum;
#pragma unroll
    for (int kt = 0; kt < 5; ++kt) pj[kt][j] *= inv;
  }

  unsigned short* pw = &Ps[w * 16 * 104];
#pragma unroll
  for (int kt = 0; kt < 5; ++kt)
#pragma unroll
    for (int j = 0; j < 4; ++j)
      pw[(lg * 4 + j) * 104 + kt * 16 + lq] = f2bf(pj[kt][j]);
#pragma unroll
  for (int j = 0; j < 4; ++j) pw[lq * 104 + 80 + lg * 4 + j] = 0;

  floatx4 o[3] = {};
#pragma unroll
  for (int c = 0; c < 3; ++c) {
    bf16x8 ap = *(const bf16x8*)&pw[lq * 104 + c * 32 + lg * 8];
#pragma unroll
    for (int nt = 0; nt < 3; ++nt) {
      bf16x8 av = *(const bf16x8*)&Vt[(nt * 16 + lq) * 152 + w * 16 + c * 32 + lg * 8];
      o[nt] = __builtin_amdgcn_mfma_f32_16x16x32_bf16(ap, av, o[nt], 0, 0, 0);
    }
  }
#pragma unroll
  for (int nt = 0; nt < 3; ++nt) {
    const int d = nt * 16 + lq;
    const int c = h * ND + d;
    const float g = gate[c];
#pragma unroll
    for (int j = 0; j < 4; ++j) {
      const int tt = qs + lg * 4 + j;
      attg[((size_t)b * NT + tt) * NC + c] = f2bf(o[nt][j] * g);
    }
  }
}

// ---------------- Kernel 3: out = attg @ WpT^T + b_proj (fp32 out)
__global__ __launch_bounds__(256) void k_proj(const unsigned short* __restrict__ A,
                                              const unsigned short* __restrict__ WpT,
                                              const float* __restrict__ bp,
                                              float* __restrict__ out) {
  __shared__ __align__(16) unsigned short As[128 * 32];
  __shared__ __align__(16) unsigned short Bs[128 * 32];
  const int t = threadIdx.x, lane = t & 63, w = t >> 6;
  const int wm = w >> 1, wn = w & 1;
  const int lq = lane & 15, lg = lane >> 4;
  const int m0 = blockIdx.x * 128, n0 = blockIdx.y * 128;
  const unsigned short* Ag = A + (size_t)(m0 + w * 32 + (lane >> 2)) * 384 + (lane & 3) * 8;
  const unsigned short* Bg = WpT + (size_t)(n0 + w * 32 + (lane >> 2)) * 384 + (lane & 3) * 8;
  unsigned short* lA0 = As + (w * 32) * 32;
  unsigned short* lA1 = As + (w * 32 + 16) * 32;
  unsigned short* lB0 = Bs + (w * 32) * 32;
  unsigned short* lB1 = Bs + (w * 32 + 16) * 32;
  floatx4 acc[4][4] = {};

  for (int k0 = 0; k0 < 384; k0 += 32) {
    __syncthreads();
    gload16(Ag + k0, lA0);
    gload16(Ag + k0 + 16 * 384, lA1);
    gload16(Bg + k0, lB0);
    gload16(Bg + k0 + 16 * 384, lB1);
    __syncthreads();
    bf16x8 a[4], b[4];
#pragma unroll
    for (int mt = 0; mt < 4; ++mt)
      a[mt] = *(const bf16x8*)&As[(wm * 64 + mt * 16 + lq) * 32 + lg * 8];
#pragma unroll
    for (int nt = 0; nt < 4; ++nt)
      b[nt] = *(const bf16x8*)&Bs[(wn * 64 + nt * 16 + lq) * 32 + lg * 8];
#pragma unroll
    for (int mt = 0; mt < 4; ++mt)
#pragma unroll
      for (int nt = 0; nt < 4; ++nt)
        acc[mt][nt] = __builtin_amdgcn_mfma_f32_16x16x32_bf16(a[mt], b[nt], acc[mt][nt], 0, 0, 0);
  }
#pragma unroll
  for (int nt = 0; nt < 4; ++nt) {
    const int col = n0 + wn * 64 + nt * 16 + lq;
    const float bias = bp[col];
#pragma unroll
    for (int mt = 0; mt < 4; ++mt)
#pragma unroll
      for (int j = 0; j < 4; ++j) {
        const int row = m0 + wm * 64 + mt * 16 + lg * 4 + j;
        out[(size_t)row * 384 + col] = acc[mt][nt][j] + bias;
      }
  }
}

extern "C" void kernel_launch(void* const* d_in, const int* in_sizes, int n_in,
                              void* d_out, int out_size, void* d_ws, size_t ws_size,
                              hipStream_t stream) {
  const float* x    = (const float*)d_in[0];
  const float* Wq   = (const float*)d_in[1];
  const float* bq   = (const float*)d_in[2];
  const float* Wp   = (const float*)d_in[3];
  const float* bp   = (const float*)d_in[4];
  const float* gate = (const float*)d_in[5];

  const size_t nx = (size_t)NB * NT * NC;               // 12,582,912
  unsigned short* xbf  = (unsigned short*)d_ws;         // also reused as attg
  unsigned short* qkvp = xbf + nx;
  unsigned short* WqT  = qkvp + (size_t)3 * NB * NH * NT * ND;
  unsigned short* WpT  = WqT + (size_t)384 * 1152;
  unsigned short* attg = xbf;                           // alias: xbf dead after k_qkv
  float* out = (float*)d_out;

  k_cvt<<<dim3(2048), 256, 0, stream>>>(x, xbf, (int)(nx / 8));
  k_twt<<<dim3(144), 256, 0, stream>>>(Wq, Wp, WqT, WpT);
  k_qkv<<<dim3(256, 9), 256, 0, stream>>>(xbf, WqT, bq, qkvp);
  k_attn<<<dim3(4096), 256, 0, stream>>>(qkvp, gate, attg);
  k_proj<<<dim3(256, 3), 256, 0, stream>>>(attg, WpT, bp, out);
}

// Round 3
// 120.845 us; speedup vs baseline: 1.5847x; 1.0111x over previous
//
#include <hip/hip_runtime.h>
#include <hip/hip_bf16.h>

typedef __attribute__((ext_vector_type(8))) short bf16x8;
typedef __attribute__((ext_vector_type(4))) float floatx4;

#define NB 128
#define NT 256
#define NC 384
#define NH 8
#define ND 48

static __device__ __forceinline__ unsigned short f2bf(float f) {
  __hip_bfloat16 h = __float2bfloat16(f);
  return __builtin_bit_cast(unsigned short, h);
}

static __device__ __forceinline__ void gload16(const unsigned short* g, unsigned short* l) {
  __builtin_amdgcn_global_load_lds(
      (const __attribute__((address_space(1))) void*)g,
      (__attribute__((address_space(3))) void*)l, 16, 0, 0);
}

// ---------------- Prep: transpose+convert W_qkv -> [1152][384] bf16, W_proj -> [384][384] bf16
__global__ __launch_bounds__(256) void k_twt(const float* __restrict__ Wq,
                                             const float* __restrict__ Wp,
                                             unsigned short* __restrict__ WqT,
                                             unsigned short* __restrict__ WpT) {
  __shared__ float T[64][65];
  int blk = blockIdx.x;
  const float* src;
  unsigned short* dst;
  int N, kt, nt;
  if (blk < 108) { src = Wq; dst = WqT; N = 1152; kt = blk / 18; nt = blk % 18; }
  else { int b2 = blk - 108; src = Wp; dst = WpT; N = 384; kt = b2 / 6; nt = b2 % 6; }
  const int k0 = kt * 64, n0 = nt * 64;
  const int t = threadIdx.x;
  const int r = t >> 2, c = (t & 3) * 16;
  const float* s = src + (size_t)(k0 + r) * N + n0 + c;
#pragma unroll
  for (int i = 0; i < 4; ++i) *(float4*)&T[r][c + i * 4] = ((const float4*)s)[i];
  __syncthreads();
  unsigned short o[16];
#pragma unroll
  for (int i = 0; i < 16; ++i) o[i] = f2bf(T[c + i][r]);
  unsigned short* dp = dst + (size_t)(n0 + r) * 384 + k0 + c;
  *(bf16x8*)dp = *(bf16x8*)&o[0];
  *(bf16x8*)(dp + 8) = *(bf16x8*)&o[8];
}

// ---------------- Kernel 1: qkv = x(fp32) @ WqT^T + b_qkv -> bf16 [3][B][H][T][48]
// 2-phase double-buffered; A reg-staged (fused fp32->bf16), B via global_load_lds.
__global__ __launch_bounds__(256) void k_qkv(const float* __restrict__ x,
                                             const unsigned short* __restrict__ WqT,
                                             const float* __restrict__ bq,
                                             unsigned short* __restrict__ qkv) {
  __shared__ __align__(16) unsigned short As[2 * 128 * 32];
  __shared__ __align__(16) unsigned short Bs[2 * 128 * 32];
  const int t = threadIdx.x, lane = t & 63, w = t >> 6;
  const int wm = w >> 1, wn = w & 1;
  const int lq = lane & 15, lg = lane >> 4;
  const int m0 = blockIdx.x * 128, n0 = blockIdx.y * 128;

  // A staging: thread t covers rows (t>>2) and 64+(t>>2), k-cols (t&3)*8..+8 (floats)
  const float* Ag0 = x + (size_t)(m0 + (t >> 2)) * 384 + (t & 3) * 8;
  const float* Ag1 = Ag0 + (size_t)64 * 384;
  // B staging: wave-uniform LDS base + lane*16B (global_load_lds)
  const unsigned short* Bg = WqT + (size_t)(n0 + w * 32 + (lane >> 2)) * 384 + (lane & 3) * 8;

  floatx4 acc[4][4] = {};
  float va[16];

#define LOADA_Q(k0)                                                   \
  {                                                                   \
    *(float4*)&va[0]  = ((const float4*)(Ag0 + (k0)))[0];             \
    *(float4*)&va[4]  = ((const float4*)(Ag0 + (k0)))[1];             \
    *(float4*)&va[8]  = ((const float4*)(Ag1 + (k0)))[0];             \
    *(float4*)&va[12] = ((const float4*)(Ag1 + (k0)))[1];             \
  }
#define WRITEA_Q(buf)                                                 \
  {                                                                   \
    bf16x8 p0, p1;                                                    \
    _Pragma("unroll") for (int i = 0; i < 8; ++i) {                   \
      p0[i] = (short)f2bf(va[i]);                                     \
      p1[i] = (short)f2bf(va[8 + i]);                                 \
    }                                                                 \
    *(bf16x8*)(As + (buf)*4096 + 8 * t) = p0;                         \
    *(bf16x8*)(As + (buf)*4096 + 2048 + 8 * t) = p1;                  \
  }
#define LOADB_Q(k0, buf)                                              \
  {                                                                   \
    gload16(Bg + (k0), Bs + (buf)*4096 + (w * 32) * 32);              \
    gload16(Bg + (k0) + 16 * 384, Bs + (buf)*4096 + (w * 32 + 16) * 32); \
  }

  // prologue: stage tile 0 into buffer 0
  LOADA_Q(0);
  LOADB_Q(0, 0);
  WRITEA_Q(0);
  __syncthreads();

  int cur = 0;
  for (int k0 = 0; k0 < 384; k0 += 32) {
    const int nk = k0 + 32;
    if (nk < 384) {  // issue next tile's loads (A->regs, B->LDS async)
      LOADA_Q(nk);
      LOADB_Q(nk, cur ^ 1);
    }
    const unsigned short* Ac = As + cur * 4096;
    const unsigned short* Bc = Bs + cur * 4096;
    bf16x8 a[4], b[4];
#pragma unroll
    for (int mt = 0; mt < 4; ++mt)
      a[mt] = *(const bf16x8*)&Ac[(wm * 64 + mt * 16 + lq) * 32 + lg * 8];
#pragma unroll
    for (int nt = 0; nt < 4; ++nt)
      b[nt] = *(const bf16x8*)&Bc[(wn * 64 + nt * 16 + lq) * 32 + lg * 8];
#pragma unroll
    for (int mt = 0; mt < 4; ++mt)
#pragma unroll
      for (int nt = 0; nt < 4; ++nt)
        acc[mt][nt] = __builtin_amdgcn_mfma_f32_16x16x32_bf16(a[mt], b[nt], acc[mt][nt], 0, 0, 0);
    if (nk < 384) WRITEA_Q(cur ^ 1);  // write-late: HBM latency hid under MFMAs
    __syncthreads();
    cur ^= 1;
  }

  // epilogue: +bias, scatter to [comp][b][h][t][d] bf16
  const int comp = n0 / 384;
  const int cb = n0 - comp * 384;
#pragma unroll
  for (int nt = 0; nt < 4; ++nt) {
    const int cc = cb + wn * 64 + nt * 16 + lq;
    const int h = cc / 48, d = cc - h * 48;
    const float bias = bq[n0 + wn * 64 + nt * 16 + lq];
#pragma unroll
    for (int mt = 0; mt < 4; ++mt) {
#pragma unroll
      for (int j = 0; j < 4; ++j) {
        const int row = m0 + wm * 64 + mt * 16 + lg * 4 + j;
        const int bb = row >> 8, tt = row & 255;
        qkv[((((size_t)comp * NB + bb) * NH + h) * NT + tt) * ND + d] =
            f2bf(acc[mt][nt][j] + bias);
      }
    }
  }
}

// ---------------- Kernel 2: windowed causal attention + gate, bf16 out [B][T][C]
__global__ __launch_bounds__(256) void k_attn(const unsigned short* __restrict__ qkv,
                                              const float* __restrict__ gate,
                                              unsigned short* __restrict__ attg) {
  __shared__ __align__(16) unsigned short Ks[128 * 72];      // [key][hd pad 64->72]
  __shared__ __align__(16) unsigned short Vt[48 * 152];      // [d][key pad 144->152]
  __shared__ __align__(16) unsigned short Ps[4 * 16 * 104];  // per-wave P [q][key pad]
  const int t = threadIdx.x;
  const int blk = blockIdx.x;
  const int tile = blk & 3;
  const int bh = blk >> 2;
  const int b = bh >> 3, h = bh & 7;
  const int base = tile * 64;
  const size_t kvoff = (size_t)bh * NT * ND;
  const unsigned short* qptr = qkv + kvoff;
  const unsigned short* kptr = qkv + (size_t)NB * NH * NT * ND + kvoff;
  const unsigned short* vptr = qkv + (size_t)2 * NB * NH * NT * ND + kvoff;

  if (t < 48) {
    bf16x8 z = {};
    *(bf16x8*)&Vt[t * 152 + 128] = z;
    *(bf16x8*)&Vt[t * 152 + 136] = z;
  }
  if (t < 128) {
    const int r = t, ka = base - 64 + r;
    unsigned short* dst = &Ks[r * 72];
    if (ka >= 0) {
      const unsigned short* src = kptr + (size_t)ka * ND;
#pragma unroll
      for (int i = 0; i < 6; ++i) *(bf16x8*)(dst + i * 8) = *(const bf16x8*)(src + i * 8);
      bf16x8 z = {};
      *(bf16x8*)(dst + 48) = z;
      *(bf16x8*)(dst + 56) = z;
    } else {
      bf16x8 z = {};
#pragma unroll
      for (int i = 0; i < 8; ++i) *(bf16x8*)(dst + i * 8) = z;
    }
  } else {
    const int r = t - 128, ka = base - 64 + r;
    if (ka >= 0) {
      const unsigned short* src = vptr + (size_t)ka * ND;
      bf16x8 vv[6];
#pragma unroll
      for (int i = 0; i < 6; ++i) vv[i] = *(const bf16x8*)(src + i * 8);
#pragma unroll
      for (int i = 0; i < 6; ++i)
#pragma unroll
        for (int j = 0; j < 8; ++j)
          Vt[(i * 8 + j) * 152 + r] = (unsigned short)vv[i][j];
    } else {
#pragma unroll
      for (int d = 0; d < 48; ++d) Vt[d * 152 + r] = 0;
    }
  }
  __syncthreads();

  const int lane = t & 63, w = t >> 6;
  const int lq = lane & 15, lg = lane >> 4;
  const int qs = base + w * 16;

  const unsigned short* qrow = qptr + (size_t)(qs + lq) * ND;
  bf16x8 aq0 = *(const bf16x8*)(qrow + lg * 8);
  bf16x8 aq1 = {};
  if (lg < 2) aq1 = *(const bf16x8*)(qrow + 32 + lg * 8);

  floatx4 s[5];
#pragma unroll
  for (int kt = 0; kt < 5; ++kt) {
    const unsigned short* kr = &Ks[(w * 16 + kt * 16 + lq) * 72];
    bf16x8 kb0 = *(const bf16x8*)(kr + lg * 8);
    bf16x8 kb1 = *(const bf16x8*)(kr + 32 + lg * 8);
    floatx4 z = {};
    z = __builtin_amdgcn_mfma_f32_16x16x32_bf16(aq0, kb0, z, 0, 0, 0);
    z = __builtin_amdgcn_mfma_f32_16x16x32_bf16(aq1, kb1, z, 0, 0, 0);
    s[kt] = z;
  }

  const float scale = 0.14433756729740643f;  // 1/sqrt(48)
  floatx4 pj[5];
#pragma unroll
  for (int j = 0; j < 4; ++j) {
    const int qa = qs + lg * 4 + j;
    float mx = -1e30f;
    float sv[5];
    bool ok[5];
#pragma unroll
    for (int kt = 0; kt < 5; ++kt) {
      const int ka = base - 64 + w * 16 + kt * 16 + lq;
      sv[kt] = s[kt][j] * scale;
      ok[kt] = (ka >= 0) && (ka <= qa) && (qa - ka <= 64);
      if (ok[kt]) mx = fmaxf(mx, sv[kt]);
    }
#pragma unroll
    for (int dd = 1; dd < 16; dd <<= 1) mx = fmaxf(mx, __shfl_xor(mx, dd));
    float sum = 0.f;
#pragma unroll
    for (int kt = 0; kt < 5; ++kt) {
      float p = ok[kt] ? __expf(sv[kt] - mx) : 0.f;
      pj[kt][j] = p;
      sum += p;
    }
#pragma unroll
    for (int dd = 1; dd < 16; dd <<= 1) sum += __shfl_xor(sum, dd);
    const float inv = 1.f / sum;
#pragma unroll
    for (int kt = 0; kt < 5; ++kt) pj[kt][j] *= inv;
  }

  unsigned short* pw = &Ps[w * 16 * 104];
#pragma unroll
  for (int kt = 0; kt < 5; ++kt)
#pragma unroll
    for (int j = 0; j < 4; ++j)
      pw[(lg * 4 + j) * 104 + kt * 16 + lq] = f2bf(pj[kt][j]);
#pragma unroll
  for (int j = 0; j < 4; ++j) pw[lq * 104 + 80 + lg * 4 + j] = 0;

  floatx4 o[3] = {};
#pragma unroll
  for (int c = 0; c < 3; ++c) {
    bf16x8 ap = *(const bf16x8*)&pw[lq * 104 + c * 32 + lg * 8];
#pragma unroll
    for (int nt = 0; nt < 3; ++nt) {
      bf16x8 av = *(const bf16x8*)&Vt[(nt * 16 + lq) * 152 + w * 16 + c * 32 + lg * 8];
      o[nt] = __builtin_amdgcn_mfma_f32_16x16x32_bf16(ap, av, o[nt], 0, 0, 0);
    }
  }
#pragma unroll
  for (int nt = 0; nt < 3; ++nt) {
    const int d = nt * 16 + lq;
    const int c = h * ND + d;
    const float g = gate[c];
#pragma unroll
    for (int j = 0; j < 4; ++j) {
      const int tt = qs + lg * 4 + j;
      attg[((size_t)b * NT + tt) * NC + c] = f2bf(o[nt][j] * g);
    }
  }
}

// ---------------- Kernel 3: out = attg @ WpT^T + b_proj (fp32 out), 2-phase dbuf
__global__ __launch_bounds__(256) void k_proj(const unsigned short* __restrict__ A,
                                              const unsigned short* __restrict__ WpT,
                                              const float* __restrict__ bp,
                                              float* __restrict__ out) {
  __shared__ __align__(16) unsigned short As[2 * 128 * 32];
  __shared__ __align__(16) unsigned short Bs[2 * 128 * 32];
  const int t = threadIdx.x, lane = t & 63, w = t >> 6;
  const int wm = w >> 1, wn = w & 1;
  const int lq = lane & 15, lg = lane >> 4;
  const int m0 = blockIdx.x * 128, n0 = blockIdx.y * 128;
  const unsigned short* Ag = A + (size_t)(m0 + w * 32 + (lane >> 2)) * 384 + (lane & 3) * 8;
  const unsigned short* Bg = WpT + (size_t)(n0 + w * 32 + (lane >> 2)) * 384 + (lane & 3) * 8;
  floatx4 acc[4][4] = {};

#define STAGE_P(k0, buf)                                                   \
  {                                                                        \
    gload16(Ag + (k0), As + (buf)*4096 + (w * 32) * 32);                   \
    gload16(Ag + (k0) + 16 * 384, As + (buf)*4096 + (w * 32 + 16) * 32);   \
    gload16(Bg + (k0), Bs + (buf)*4096 + (w * 32) * 32);                   \
    gload16(Bg + (k0) + 16 * 384, Bs + (buf)*4096 + (w * 32 + 16) * 32);   \
  }

  STAGE_P(0, 0);
  __syncthreads();

  int cur = 0;
  for (int k0 = 0; k0 < 384; k0 += 32) {
    const int nk = k0 + 32;
    if (nk < 384) STAGE_P(nk, cur ^ 1);
    const unsigned short* Ac = As + cur * 4096;
    const unsigned short* Bc = Bs + cur * 4096;
    bf16x8 a[4], b[4];
#pragma unroll
    for (int mt = 0; mt < 4; ++mt)
      a[mt] = *(const bf16x8*)&Ac[(wm * 64 + mt * 16 + lq) * 32 + lg * 8];
#pragma unroll
    for (int nt = 0; nt < 4; ++nt)
      b[nt] = *(const bf16x8*)&Bc[(wn * 64 + nt * 16 + lq) * 32 + lg * 8];
#pragma unroll
    for (int mt = 0; mt < 4; ++mt)
#pragma unroll
      for (int nt = 0; nt < 4; ++nt)
        acc[mt][nt] = __builtin_amdgcn_mfma_f32_16x16x32_bf16(a[mt], b[nt], acc[mt][nt], 0, 0, 0);
    __syncthreads();
    cur ^= 1;
  }
#pragma unroll
  for (int nt = 0; nt < 4; ++nt) {
    const int col = n0 + wn * 64 + nt * 16 + lq;
    const float bias = bp[col];
#pragma unroll
    for (int mt = 0; mt < 4; ++mt)
#pragma unroll
      for (int j = 0; j < 4; ++j) {
        const int row = m0 + wm * 64 + mt * 16 + lg * 4 + j;
        out[(size_t)row * 384 + col] = acc[mt][nt][j] + bias;
      }
  }
}

extern "C" void kernel_launch(void* const* d_in, const int* in_sizes, int n_in,
                              void* d_out, int out_size, void* d_ws, size_t ws_size,
                              hipStream_t stream) {
  const float* x    = (const float*)d_in[0];
  const float* Wq   = (const float*)d_in[1];
  const float* bq   = (const float*)d_in[2];
  const float* Wp   = (const float*)d_in[3];
  const float* bp   = (const float*)d_in[4];
  const float* gate = (const float*)d_in[5];

  const size_t nx = (size_t)NB * NT * NC;                // 12,582,912
  unsigned short* attg = (unsigned short*)d_ws;
  unsigned short* qkvp = attg + nx;
  unsigned short* WqT  = qkvp + (size_t)3 * NB * NH * NT * ND;
  unsigned short* WpT  = WqT + (size_t)384 * 1152;
  float* out = (float*)d_out;

  k_twt<<<dim3(144), 256, 0, stream>>>(Wq, Wp, WqT, WpT);
  k_qkv<<<dim3(256, 9), 256, 0, stream>>>(x, WqT, bq, qkvp);
  k_attn<<<dim3(4096), 256, 0, stream>>>(qkvp, gate, attg);
  k_proj<<<dim3(256, 3), 256, 0, stream>>>(attg, WpT, bp, out);
}